// Round 6
// baseline (521.263 us; speedup 1.0000x reference)
//
#include <hip/hip_runtime.h>

// GNN layer: messages = relu(NF @ Wm^T + bm); agg = (adj @ messages)/deg; GRU(agg, NF)
// N=8192, D=128. adj read 268 MB = the floor. bf16 MFMA 16x16x32.
// V6: K2 redesigned after V4/V5's allocator failure (VGPR pinned at 64, 120MB spill
// traffic, 163us at 4% util twice). New K2: wave-level k-split (8 waves x 1024-k per
// 16-row block, 4096 waves = 16/CU), ZERO barriers in main loop, both MFMA operands
// global->reg in fragment layout (V3's proven codegen path), X/Y reg double-buffer,
// packed int->bf16 convert (2 ops/pair) with degree folded into one running sum,
// cross-wave reduce via 64KB LDS + single barrier, final bf16 agg written (no 32MB
// f32 partials). K3 reverts to direct-agg form. K1 unchanged (verified).

#define NN 8192
#define DIM 128
#define LSTR 136  // 128 + 8 bf16 pad (K1/K3 LDS tiles)

typedef __bf16 bf16x8 __attribute__((ext_vector_type(8)));
typedef float f32x4 __attribute__((ext_vector_type(4)));

__device__ __forceinline__ unsigned short f2bf(float f) {
  union { float f; unsigned u; } v; v.f = f;
  unsigned r = v.u + 0x7FFF + ((v.u >> 16) & 1);  // RNE
  return (unsigned short)(r >> 16);
}
__device__ __forceinline__ ushort4 f2bf4(float4 f) {
  ushort4 u; u.x = f2bf(f.x); u.y = f2bf(f.y); u.z = f2bf(f.z); u.w = f2bf(f.w);
  return u;
}
__device__ __forceinline__ float sigmoidf_(float x) {
  return 1.0f / (1.0f + __expf(-x));
}
__device__ __forceinline__ float tanhf_(float x) {
  float e = __expf(-2.0f * fabsf(x));
  float r = (1.0f - e) / (1.0f + e);
  return x < 0.0f ? -r : r;
}
// two 0/1 ints -> packed bf16 pair {0.0,1.0}; tsum accumulates lo in bits[15:0],
// hi in bits[31:16] (max 128 adds each half -- no overflow for k<=1024 per lane).
__device__ __forceinline__ unsigned pack2(int lo, int hi, unsigned& tsum) {
  unsigned t = (unsigned)lo + ((unsigned)hi << 16);
  tsum += t;
  return t * 0x3F80u;
}
__device__ __forceinline__ bf16x8 adj2bf_t(const int4 lo, const int4 hi, unsigned& tsum) {
  union { unsigned u[4]; bf16x8 v; } r;
  r.u[0] = pack2(lo.x, lo.y, tsum);
  r.u[1] = pack2(lo.z, lo.w, tsum);
  r.u[2] = pack2(hi.x, hi.y, tsum);
  r.u[3] = pack2(hi.z, hi.w, tsum);
  return r.v;
}

// ---------------- K1: msgT[o][m] = relu(NF @ Wm^T + bm) (bf16, transposed).
// Side jobs: nfB = bf16(nf), wihB/whhB = bf16 GRU weights (converted once).
__global__ __launch_bounds__(256) void k1_msg(
    const float* __restrict__ nf, const float* __restrict__ w_msg,
    const float* __restrict__ b_msg, unsigned short* __restrict__ msgT,
    unsigned short* __restrict__ nfB, const float* __restrict__ w_ih,
    const float* __restrict__ w_hh, unsigned short* __restrict__ wihB,
    unsigned short* __restrict__ whhB) {
  __shared__ unsigned short wm[128 * LSTR];   // wm[o][k] bf16
  __shared__ unsigned short nfl[32 * LSTR];   // nf tile [m][k] bf16
  const int t = threadIdx.x;
  const int m0 = blockIdx.x * 32;

  const int gtid = blockIdx.x * 256 + t;
  if (gtid < 12288) {
    ((ushort4*)wihB)[gtid] = f2bf4(((const float4*)w_ih)[gtid]);
  } else if (gtid < 24576) {
    ((ushort4*)whhB)[gtid - 12288] = f2bf4(((const float4*)w_hh)[gtid - 12288]);
  }
  for (int i = t; i < 4096; i += 256) {
    float4 v = ((const float4*)w_msg)[i];
    const int row = i >> 5, col = (i & 31) * 4;
    *(ushort4*)&wm[row * LSTR + col] = f2bf4(v);
  }
  for (int i = t; i < 1024; i += 256) {
    float4 v = ((const float4*)(nf + m0 * 128))[i];
    ushort4 u = f2bf4(v);
    const int row = i >> 5, col = (i & 31) * 4;
    *(ushort4*)&nfl[row * LSTR + col] = u;
    *(ushort4*)&nfB[(m0 + row) * 128 + col] = u;
  }
  __syncthreads();

  const int lane = t & 63, wave = t >> 6;
  const int quad = lane >> 4, l16 = lane & 15;
  const int rt = wave >> 1, ch = wave & 1;
  f32x4 acc[4];
  for (int j = 0; j < 4; ++j) acc[j] = (f32x4){0.f, 0.f, 0.f, 0.f};
  for (int kk = 0; kk < 4; ++kk) {
    bf16x8 a = *(const bf16x8*)&nfl[(rt * 16 + l16) * LSTR + kk * 32 + quad * 8];
    for (int j = 0; j < 4; ++j) {
      const int ct = ch * 4 + j;
      bf16x8 b = *(const bf16x8*)&wm[(ct * 16 + l16) * LSTR + kk * 32 + quad * 8];
      acc[j] = __builtin_amdgcn_mfma_f32_16x16x32_bf16(a, b, acc[j], 0, 0, 0);
    }
  }
  const int mb = m0 + rt * 16 + quad * 4;
  for (int j = 0; j < 4; ++j) {
    const int o = (ch * 4 + j) * 16 + l16;
    const float bias = b_msg[o];
    ushort4 u;
    u.x = f2bf(fmaxf(acc[j][0] + bias, 0.0f));
    u.y = f2bf(fmaxf(acc[j][1] + bias, 0.0f));
    u.z = f2bf(fmaxf(acc[j][2] + bias, 0.0f));
    u.w = f2bf(fmaxf(acc[j][3] + bias, 0.0f));
    *(ushort4*)&msgT[o * NN + mb] = u;
  }
}

// ---------------- K2: block = 16 output rows, 8 waves x disjoint 1024-k chunks.
// Main loop barrier-free: A (adj) HBM->reg 128B/row contiguous, B (msgT) L2->reg
// in fragment layout, X/Y double-buffer. One barrier for the 8-way LDS reduce,
// then final agg = sum/deg in bf16. Grid 512 x 512thr -> 4096 waves (16/CU).
__global__ __launch_bounds__(512) void k2_agg(
    const int* __restrict__ adj, const unsigned short* __restrict__ msgT,
    unsigned short* __restrict__ agg) {
  __shared__ float red[8][16][128];   // 64 KB: per-wave partials
  __shared__ int degW[8][16];
  const int t = threadIdx.x;
  const int lane = t & 63, wave = t >> 6;
  const int l16 = lane & 15, quad = lane >> 4;
  const int m0 = blockIdx.x * 16;
  const int kw = wave * 1024 + quad * 8;   // this wave's k-chunk + quad offset

  const int* aP = adj + (size_t)(m0 + l16) * NN + kw;          // row m0+l16
  const unsigned short* bP = msgT + (size_t)l16 * NN + kw;     // o-row l16 (+ct*16 rows)

  f32x4 acc[8];
#pragma unroll
  for (int ct = 0; ct < 8; ++ct) acc[ct] = (f32x4){0.f, 0.f, 0.f, 0.f};
  unsigned tsum = 0;

  int4 xa0, xa1, ya0, ya1;
  bf16x8 xb[8], yb[8];

#define K2_LDA(a0, a1, ko) do { \
    a0 = *(const int4*)(aP + (ko)); a1 = *(const int4*)(aP + (ko) + 4); } while (0)
#define K2_LDB(bv, ko) do { _Pragma("unroll") \
    for (int ct = 0; ct < 8; ++ct) \
      bv[ct] = *(const bf16x8*)(bP + (size_t)ct * (16 * NN) + (ko)); } while (0)
#define K2_CMP(a0, a1, bv) do { \
    bf16x8 fa = adj2bf_t(a0, a1, tsum); \
    _Pragma("unroll") \
    for (int ct = 0; ct < 8; ++ct) \
      acc[ct] = __builtin_amdgcn_mfma_f32_16x16x32_bf16(fa, bv[ct], acc[ct], 0, 0, 0); \
  } while (0)

  K2_LDA(xa0, xa1, 0);
  K2_LDB(xb, 0);
  for (int it = 0; it < 32; it += 2) {
    K2_LDA(ya0, ya1, (it + 1) * 32);
    K2_LDB(yb, (it + 1) * 32);
    K2_CMP(xa0, xa1, xb);
    if (it + 2 < 32) {
      K2_LDA(xa0, xa1, (it + 2) * 32);
      K2_LDB(xb, (it + 2) * 32);
    }
    K2_CMP(ya0, ya1, yb);
  }
#undef K2_LDA
#undef K2_LDB
#undef K2_CMP

  // fold degree: lo half counts even elems, hi half odd elems; then quad-reduce
  int deg = (int)(tsum & 0xFFFFu) + (int)(tsum >> 16);
  deg += __shfl_xor(deg, 16);
  deg += __shfl_xor(deg, 32);
  if (lane < 16) degW[wave][lane] = deg;

#pragma unroll
  for (int ct = 0; ct < 8; ++ct)
#pragma unroll
    for (int r = 0; r < 4; ++r)
      red[wave][quad * 4 + r][ct * 16 + l16] = acc[ct][r];
  __syncthreads();

  // combine: thread t covers row t>>5, cols (t&31)*4 .. +3
  {
    const int row = t >> 5, c4 = (t & 31) * 4;
    float4 s = {0.f, 0.f, 0.f, 0.f};
    int dg = 0;
#pragma unroll
    for (int w = 0; w < 8; ++w) {
      const float4 v = *(const float4*)&red[w][row][c4];
      s.x += v.x; s.y += v.y; s.z += v.z; s.w += v.w;
      dg += degW[w][row];
    }
    const float inv = 1.0f / fmaxf((float)dg, 1.0f);
    s.x *= inv; s.y *= inv; s.z *= inv; s.w *= inv;
    *(ushort4*)&agg[(size_t)(m0 + row) * 128 + c4] = f2bf4(s);
  }
}

// ---------------- K3: fused GRU, 512 thr / 32-row tiles (grid 256).
// agg already bf16+normalized; B-frags direct from bf16 weights (L2-resident),
// 1 barrier total.
__global__ __launch_bounds__(512) void k3_gru(
    const float* __restrict__ nf, const unsigned short* __restrict__ agg,
    const unsigned short* __restrict__ wihB, const unsigned short* __restrict__ whhB,
    const float* __restrict__ b_ih, const float* __restrict__ b_hh,
    const unsigned short* __restrict__ nfB, float* __restrict__ out) {
  __shared__ unsigned short aggL[32 * LSTR];
  __shared__ unsigned short nfL[32 * LSTR];
  const int t = threadIdx.x;
  const int m0 = blockIdx.x * 32;
  {
    const int r_ = t >> 4, c8 = (t & 15) * 8;  // 512 thr cover 32 rows x 128 cols
    *(int4*)&aggL[r_ * LSTR + c8] = *(const int4*)&agg[(size_t)(m0 + r_) * 128 + c8];
    *(int4*)&nfL[r_ * LSTR + c8] = *(const int4*)&nfB[(size_t)(m0 + r_) * 128 + c8];
  }
  __syncthreads();

  const int lane = t & 63, wave = t >> 6;
  const int quad = lane >> 4, l16 = lane & 15;
  const int rt = wave >> 2;                       // 2 row-tiles of 16
  const int ct0 = (wave & 3) * 2, ct1 = ct0 + 1;  // 2 col-tiles per wave

  bf16x8 aA[4], aN[4];
  for (int kk = 0; kk < 4; ++kk) {
    aA[kk] = *(const bf16x8*)&aggL[(rt * 16 + l16) * LSTR + kk * 32 + quad * 8];
    aN[kk] = *(const bf16x8*)&nfL[(rt * 16 + l16) * LSTR + kk * 32 + quad * 8];
  }

  float gate[2][4];
  const int order[3] = {0, 2, 1};  // r -> n -> z
  for (int ci = 0; ci < 3; ++ci) {
    const int c = order[ci];
    f32x4 ai[2], ah[2];
    for (int j = 0; j < 2; ++j) {
      const int o = (j ? ct1 : ct0) * 16 + l16;
      const unsigned short* wb = wihB + c * 16384 + o * 128;
      f32x4 acc = {0.f, 0.f, 0.f, 0.f};
      for (int kk = 0; kk < 4; ++kk) {
        bf16x8 b = *(const bf16x8*)&wb[kk * 32 + quad * 8];
        acc = __builtin_amdgcn_mfma_f32_16x16x32_bf16(aA[kk], b, acc, 0, 0, 0);
      }
      ai[j] = acc;
    }
    for (int j = 0; j < 2; ++j) {
      const int o = (j ? ct1 : ct0) * 16 + l16;
      const unsigned short* wb = whhB + c * 16384 + o * 128;
      f32x4 acc = {0.f, 0.f, 0.f, 0.f};
      for (int kk = 0; kk < 4; ++kk) {
        bf16x8 b = *(const bf16x8*)&wb[kk * 32 + quad * 8];
        acc = __builtin_amdgcn_mfma_f32_16x16x32_bf16(aN[kk], b, acc, 0, 0, 0);
      }
      ah[j] = acc;
    }
    for (int j = 0; j < 2; ++j) {
      const int col = (j ? ct1 : ct0) * 16 + l16;
      const float bi = b_ih[c * 128 + col];
      const float bh = b_hh[c * 128 + col];
      for (int r = 0; r < 4; ++r) {
        const float gi = ai[j][r] + bi;
        const float gh = ah[j][r] + bh;
        if (c == 0) {
          gate[j][r] = sigmoidf_(gi + gh);                 // r
        } else if (c == 2) {
          gate[j][r] = tanhf_(gi + gate[j][r] * gh);       // n = tanh(i_n + r*h_n)
        } else {
          const float z = sigmoidf_(gi + gh);
          const int m = m0 + rt * 16 + quad * 4 + r;
          const float h = nf[m * 128 + col];
          out[m * 128 + col] = (1.0f - z) * gate[j][r] + z * h;
        }
      }
    }
  }
}

extern "C" void kernel_launch(void* const* d_in, const int* in_sizes, int n_in,
                              void* d_out, int out_size, void* d_ws, size_t ws_size,
                              hipStream_t stream) {
  const float* nf   = (const float*)d_in[0];
  const int*   adj  = (const int*)d_in[1];
  const float* wmsg = (const float*)d_in[2];
  const float* bmsg = (const float*)d_in[3];
  const float* wih  = (const float*)d_in[4];
  const float* whh  = (const float*)d_in[5];
  const float* bih  = (const float*)d_in[6];
  const float* bhh  = (const float*)d_in[7];
  float* out = (float*)d_out;

  // ws: msgT 2MB | nfB 2MB | agg 2MB | wihB 96KB | whhB 96KB
  unsigned short* msgT = (unsigned short*)d_ws;
  unsigned short* nfB  = msgT + (size_t)NN * DIM;
  unsigned short* aggB = nfB + (size_t)NN * DIM;
  unsigned short* wihB = aggB + (size_t)NN * DIM;
  unsigned short* whhB = wihB + 3 * DIM * DIM;

  k1_msg<<<NN / 32, 256, 0, stream>>>(nf, wmsg, bmsg, msgT, nfB, wih, whh, wihB, whhB);
  k2_agg<<<NN / 16, 512, 0, stream>>>(adj, msgT, aggB);
  k3_gru<<<NN / 32, 512, 0, stream>>>(nf, aggB, wihB, whhB, bih, bhh, nfB, out);
}

// Round 7
// 416.747 us; speedup vs baseline: 1.2508x; 1.2508x over previous
//
#include <hip/hip_runtime.h>

// GNN layer: messages = relu(NF @ Wm^T + bm); agg = (adj @ messages)/deg; GRU(agg, NF)
// N=8192, D=128. adj read 268 MB = the floor. bf16 MFMA 16x16x32.
// V7: K2 reverts to the V2/R1 template -- the ONLY structure that hit ~104us --
// with k-split 2->8. Lesson from V3-V6: hipcc pins 512-thr kernels at 64-68 VGPR
// (launch_bounds ignored); fat register pipelines spill (V4/V5) or serialize (V6).
// V2's recipe = small state (acc 8 VGPR, 6-int4 prefetch) + max waves. Its 43.6 KB
// LDS allows 3 blocks/CU = 24 waves/CU; k-split=8 (grid 2048) actually sustains that
// (V2's grid 512 gave only 2/CU). K3 = R5's verified KSPLIT-combine. K1 unchanged.

#define NN 8192
#define DIM 128
#define LSTR 136  // 128 + 8 bf16 pad
#define KSPLIT 8

typedef __bf16 bf16x8 __attribute__((ext_vector_type(8)));
typedef float f32x4 __attribute__((ext_vector_type(4)));

__device__ __forceinline__ unsigned short f2bf(float f) {
  union { float f; unsigned u; } v; v.f = f;
  unsigned r = v.u + 0x7FFF + ((v.u >> 16) & 1);  // RNE
  return (unsigned short)(r >> 16);
}
__device__ __forceinline__ ushort4 f2bf4(float4 f) {
  ushort4 u; u.x = f2bf(f.x); u.y = f2bf(f.y); u.z = f2bf(f.z); u.w = f2bf(f.w);
  return u;
}
__device__ __forceinline__ float sigmoidf_(float x) {
  return 1.0f / (1.0f + __expf(-x));
}
__device__ __forceinline__ float tanhf_(float x) {
  float e = __expf(-2.0f * fabsf(x));
  float r = (1.0f - e) / (1.0f + e);
  return x < 0.0f ? -r : r;
}

// ---------------- K1: msgT[o][m] = relu(NF @ Wm^T + bm) (bf16, transposed).
// Side jobs: nfB = bf16(nf), wihB/whhB = bf16 GRU weights (converted once).
__global__ __launch_bounds__(256) void k1_msg(
    const float* __restrict__ nf, const float* __restrict__ w_msg,
    const float* __restrict__ b_msg, unsigned short* __restrict__ msgT,
    unsigned short* __restrict__ nfB, const float* __restrict__ w_ih,
    const float* __restrict__ w_hh, unsigned short* __restrict__ wihB,
    unsigned short* __restrict__ whhB) {
  __shared__ unsigned short wm[128 * LSTR];   // wm[o][k] bf16
  __shared__ unsigned short nfl[32 * LSTR];   // nf tile [m][k] bf16
  const int t = threadIdx.x;
  const int m0 = blockIdx.x * 32;

  const int gtid = blockIdx.x * 256 + t;
  if (gtid < 12288) {
    ((ushort4*)wihB)[gtid] = f2bf4(((const float4*)w_ih)[gtid]);
  } else if (gtid < 24576) {
    ((ushort4*)whhB)[gtid - 12288] = f2bf4(((const float4*)w_hh)[gtid - 12288]);
  }
  for (int i = t; i < 4096; i += 256) {
    float4 v = ((const float4*)w_msg)[i];
    const int row = i >> 5, col = (i & 31) * 4;
    *(ushort4*)&wm[row * LSTR + col] = f2bf4(v);
  }
  for (int i = t; i < 1024; i += 256) {
    float4 v = ((const float4*)(nf + m0 * 128))[i];
    ushort4 u = f2bf4(v);
    const int row = i >> 5, col = (i & 31) * 4;
    *(ushort4*)&nfl[row * LSTR + col] = u;
    *(ushort4*)&nfB[(m0 + row) * 128 + col] = u;
  }
  __syncthreads();

  const int lane = t & 63, wave = t >> 6;
  const int quad = lane >> 4, l16 = lane & 15;
  const int rt = wave >> 1, ch = wave & 1;
  f32x4 acc[4];
  for (int j = 0; j < 4; ++j) acc[j] = (f32x4){0.f, 0.f, 0.f, 0.f};
  for (int kk = 0; kk < 4; ++kk) {
    bf16x8 a = *(const bf16x8*)&nfl[(rt * 16 + l16) * LSTR + kk * 32 + quad * 8];
    for (int j = 0; j < 4; ++j) {
      const int ct = ch * 4 + j;
      bf16x8 b = *(const bf16x8*)&wm[(ct * 16 + l16) * LSTR + kk * 32 + quad * 8];
      acc[j] = __builtin_amdgcn_mfma_f32_16x16x32_bf16(a, b, acc[j], 0, 0, 0);
    }
  }
  const int mb = m0 + rt * 16 + quad * 4;
  for (int j = 0; j < 4; ++j) {
    const int o = (ch * 4 + j) * 16 + l16;
    const float bias = b_msg[o];
    ushort4 u;
    u.x = f2bf(fmaxf(acc[j][0] + bias, 0.0f));
    u.y = f2bf(fmaxf(acc[j][1] + bias, 0.0f));
    u.z = f2bf(fmaxf(acc[j][2] + bias, 0.0f));
    u.w = f2bf(fmaxf(acc[j][3] + bias, 0.0f));
    *(ushort4*)&msgT[o * NN + mb] = u;
  }
}

// ---------------- K2: V2/R1 template, k-split=8. 2048 WGs x 512 thr (8 waves).
// M-tile 32, BK 128, register-prefetch into single-buffer LDS, 2 barriers/iter,
// small per-thread state (acc 8 VGPR + 6 int4 prefetch) -> no spill at the
// compiler's 64-68 VGPR budget. LDS 43.6 KB -> 3 blocks/CU = 24 waves/CU.
__global__ __launch_bounds__(512) void k2_agg(
    const int* __restrict__ adj, const unsigned short* __restrict__ msgT,
    float* __restrict__ aggP, int* __restrict__ degP) {
  __shared__ unsigned short adjL[32 * LSTR];   // A tile [m][k] bf16 (0/1)
  __shared__ unsigned short msgL[128 * LSTR];  // B tile [o][k] bf16 (from msgT)
  __shared__ int degS[32];
  const int t = threadIdx.x;
  const int mt = blockIdx.x & 255;  // 256 m-tiles of 32 rows
  const int ks = blockIdx.x >> 8;   // 8 k-chunks of 1024
  const int m0 = mt * 32;
  const int kbase = ks * 1024;
  if (t < 32) degS[t] = 0;

  // adj staging: 32 rows x 128 ints = 1024 int4; thread t does rows (t>>5), 16+(t>>5)
  const int ar = t >> 5;         // 0..15
  const int as = t & 31;         // int4 segment within row
  // msg staging: 128 rows x 128 bf16; rows mn, mn+32, mn+64, mn+96
  const int mn = t >> 4;         // 0..31
  const int mko = (t & 15) * 8;  // element offset in k

  const int* aB0 = adj + (size_t)(m0 + ar) * NN + kbase + as * 4;
  const int* aB1 = aB0 + (size_t)16 * NN;
  const unsigned short* mB0 = msgT + (size_t)(mn +  0) * NN + kbase + mko;
  const unsigned short* mB1 = msgT + (size_t)(mn + 32) * NN + kbase + mko;
  const unsigned short* mB2 = msgT + (size_t)(mn + 64) * NN + kbase + mko;
  const unsigned short* mB3 = msgT + (size_t)(mn + 96) * NN + kbase + mko;

  int deg0 = 0, deg1 = 0;
  int4 pa0 = *(const int4*)aB0;
  int4 pa1 = *(const int4*)aB1;
  int4 pm0 = *(const int4*)mB0;
  int4 pm1 = *(const int4*)mB1;
  int4 pm2 = *(const int4*)mB2;
  int4 pm3 = *(const int4*)mB3;

  const int lane = t & 63, wave = t >> 6;
  const int quad = lane >> 4, l16 = lane & 15;
  const int rt = wave >> 2;              // waves 0-3: rows 0-15; 4-7: rows 16-31
  const int ct0 = (wave & 3) * 2, ct1 = ct0 + 1;
  f32x4 acc0 = {0.f, 0.f, 0.f, 0.f}, acc1 = {0.f, 0.f, 0.f, 0.f};

  const int aOff  = (rt * 16 + l16) * LSTR + quad * 8;
  const int bOff0 = (ct0 * 16 + l16) * LSTR + quad * 8;
  const int bOff1 = (ct1 * 16 + l16) * LSTR + quad * 8;

  for (int c = 0; c < 8; ++c) {
    // drain prefetch regs -> LDS (int 0/1 -> bf16), accumulate degree for free
    ushort4 w0, w1;
    w0.x = pa0.x ? 0x3F80 : 0; w0.y = pa0.y ? 0x3F80 : 0;
    w0.z = pa0.z ? 0x3F80 : 0; w0.w = pa0.w ? 0x3F80 : 0;
    w1.x = pa1.x ? 0x3F80 : 0; w1.y = pa1.y ? 0x3F80 : 0;
    w1.z = pa1.z ? 0x3F80 : 0; w1.w = pa1.w ? 0x3F80 : 0;
    deg0 += pa0.x + pa0.y + pa0.z + pa0.w;
    deg1 += pa1.x + pa1.y + pa1.z + pa1.w;
    *(ushort4*)&adjL[ar * LSTR + as * 4] = w0;
    *(ushort4*)&adjL[(16 + ar) * LSTR + as * 4] = w1;
    *(int4*)&msgL[(mn +  0) * LSTR + mko] = pm0;
    *(int4*)&msgL[(mn + 32) * LSTR + mko] = pm1;
    *(int4*)&msgL[(mn + 64) * LSTR + mko] = pm2;
    *(int4*)&msgL[(mn + 96) * LSTR + mko] = pm3;
    __syncthreads();
    if (c < 7) {  // next chunk's loads fly across the compute phase
      const int k0 = (c + 1) * 128;
      pa0 = *(const int4*)(aB0 + k0);
      pa1 = *(const int4*)(aB1 + k0);
      pm0 = *(const int4*)(mB0 + k0);
      pm1 = *(const int4*)(mB1 + k0);
      pm2 = *(const int4*)(mB2 + k0);
      pm3 = *(const int4*)(mB3 + k0);
    }
    for (int kk = 0; kk < 4; ++kk) {
      bf16x8 a  = *(const bf16x8*)&adjL[aOff  + kk * 32];
      bf16x8 b0 = *(const bf16x8*)&msgL[bOff0 + kk * 32];
      bf16x8 b1 = *(const bf16x8*)&msgL[bOff1 + kk * 32];
      acc0 = __builtin_amdgcn_mfma_f32_16x16x32_bf16(a, b0, acc0, 0, 0, 0);
      acc1 = __builtin_amdgcn_mfma_f32_16x16x32_bf16(a, b1, acc1, 0, 0, 0);
    }
    __syncthreads();
  }
  atomicAdd(&degS[ar], deg0);
  atomicAdd(&degS[16 + ar], deg1);
  __syncthreads();
  float* dst = aggP + (size_t)ks * NN * 128;
  if (t < 32) degP[ks * NN + m0 + t] = degS[t];
  for (int r = 0; r < 4; ++r) {
    const int rowL = rt * 16 + quad * 4 + r;
    const int m = m0 + rowL;
    dst[(size_t)m * 128 + ct0 * 16 + l16] = acc0[r];
    dst[(size_t)m * 128 + ct1 * 16 + l16] = acc1[r];
  }
}

// ---------------- K3: fused GRU, 512 thr / 32-row tiles (grid 256).
// agg = (sum_ks P_ks)/deg combined f32 at staging; B-frags direct from bf16
// weights (L2-resident), 1 barrier total.
__global__ __launch_bounds__(512) void k3_gru(
    const float* __restrict__ nf, const float* __restrict__ aggP,
    const int* __restrict__ degP, const unsigned short* __restrict__ wihB,
    const unsigned short* __restrict__ whhB, const float* __restrict__ b_ih,
    const float* __restrict__ b_hh, const unsigned short* __restrict__ nfB,
    float* __restrict__ out) {
  __shared__ unsigned short aggL[32 * LSTR];
  __shared__ unsigned short nfL[32 * LSTR];
  const int t = threadIdx.x;
  const int m0 = blockIdx.x * 32;
  {
    const int r_ = t >> 4, c8 = (t & 15) * 8;  // 512 thr cover 32 rows x 128 cols
    int dsum = 0;
#pragma unroll
    for (int ks = 0; ks < KSPLIT; ++ks) dsum += degP[ks * NN + m0 + r_];
    const float inv = 1.0f / fmaxf((float)dsum, 1.0f);
    float4 s0 = {0.f, 0.f, 0.f, 0.f}, s1 = {0.f, 0.f, 0.f, 0.f};
#pragma unroll
    for (int ks = 0; ks < KSPLIT; ++ks) {
      const float* p = aggP + ((size_t)ks * NN + m0 + r_) * 128 + c8;
      float4 a0 = *(const float4*)p, a1 = *(const float4*)(p + 4);
      s0.x += a0.x; s0.y += a0.y; s0.z += a0.z; s0.w += a0.w;
      s1.x += a1.x; s1.y += a1.y; s1.z += a1.z; s1.w += a1.w;
    }
    s0.x *= inv; s0.y *= inv; s0.z *= inv; s0.w *= inv;
    s1.x *= inv; s1.y *= inv; s1.z *= inv; s1.w *= inv;
    *(ushort4*)&aggL[r_ * LSTR + c8] = f2bf4(s0);
    *(ushort4*)&aggL[r_ * LSTR + c8 + 4] = f2bf4(s1);
    *(int4*)&nfL[r_ * LSTR + c8] = *(const int4*)&nfB[(size_t)(m0 + r_) * 128 + c8];
  }
  __syncthreads();

  const int lane = t & 63, wave = t >> 6;
  const int quad = lane >> 4, l16 = lane & 15;
  const int rt = wave >> 2;                       // 2 row-tiles of 16
  const int ct0 = (wave & 3) * 2, ct1 = ct0 + 1;  // 2 col-tiles per wave

  bf16x8 aA[4], aN[4];
  for (int kk = 0; kk < 4; ++kk) {
    aA[kk] = *(const bf16x8*)&aggL[(rt * 16 + l16) * LSTR + kk * 32 + quad * 8];
    aN[kk] = *(const bf16x8*)&nfL[(rt * 16 + l16) * LSTR + kk * 32 + quad * 8];
  }

  float gate[2][4];
  const int order[3] = {0, 2, 1};  // r -> n -> z
  for (int ci = 0; ci < 3; ++ci) {
    const int c = order[ci];
    f32x4 ai[2], ah[2];
    for (int j = 0; j < 2; ++j) {
      const int o = (j ? ct1 : ct0) * 16 + l16;
      const unsigned short* wb = wihB + c * 16384 + o * 128;
      f32x4 acc = {0.f, 0.f, 0.f, 0.f};
      for (int kk = 0; kk < 4; ++kk) {
        bf16x8 b = *(const bf16x8*)&wb[kk * 32 + quad * 8];
        acc = __builtin_amdgcn_mfma_f32_16x16x32_bf16(aA[kk], b, acc, 0, 0, 0);
      }
      ai[j] = acc;
    }
    for (int j = 0; j < 2; ++j) {
      const int o = (j ? ct1 : ct0) * 16 + l16;
      const unsigned short* wb = whhB + c * 16384 + o * 128;
      f32x4 acc = {0.f, 0.f, 0.f, 0.f};
      for (int kk = 0; kk < 4; ++kk) {
        bf16x8 b = *(const bf16x8*)&wb[kk * 32 + quad * 8];
        acc = __builtin_amdgcn_mfma_f32_16x16x32_bf16(aN[kk], b, acc, 0, 0, 0);
      }
      ah[j] = acc;
    }
    for (int j = 0; j < 2; ++j) {
      const int col = (j ? ct1 : ct0) * 16 + l16;
      const float bi = b_ih[c * 128 + col];
      const float bh = b_hh[c * 128 + col];
      for (int r = 0; r < 4; ++r) {
        const float gi = ai[j][r] + bi;
        const float gh = ah[j][r] + bh;
        if (c == 0) {
          gate[j][r] = sigmoidf_(gi + gh);                 // r
        } else if (c == 2) {
          gate[j][r] = tanhf_(gi + gate[j][r] * gh);       // n = tanh(i_n + r*h_n)
        } else {
          const float z = sigmoidf_(gi + gh);
          const int m = m0 + rt * 16 + quad * 4 + r;
          const float h = nf[m * 128 + col];
          out[m * 128 + col] = (1.0f - z) * gate[j][r] + z * h;
        }
      }
    }
  }
}

extern "C" void kernel_launch(void* const* d_in, const int* in_sizes, int n_in,
                              void* d_out, int out_size, void* d_ws, size_t ws_size,
                              hipStream_t stream) {
  const float* nf   = (const float*)d_in[0];
  const int*   adj  = (const int*)d_in[1];
  const float* wmsg = (const float*)d_in[2];
  const float* bmsg = (const float*)d_in[3];
  const float* wih  = (const float*)d_in[4];
  const float* whh  = (const float*)d_in[5];
  const float* bih  = (const float*)d_in[6];
  const float* bhh  = (const float*)d_in[7];
  float* out = (float*)d_out;

  // ws: msgT 2MB | nfB 2MB | aggP 32MB | degP 256KB | wihB 96KB | whhB 96KB
  unsigned short* msgT = (unsigned short*)d_ws;
  unsigned short* nfB  = msgT + (size_t)NN * DIM;
  float* aggP          = (float*)(nfB + (size_t)NN * DIM);
  int* degP            = (int*)(aggP + (size_t)KSPLIT * NN * DIM);
  unsigned short* wihB = (unsigned short*)(degP + KSPLIT * NN);
  unsigned short* whhB = wihB + 3 * DIM * DIM;

  k1_msg<<<NN / 32, 256, 0, stream>>>(nf, wmsg, bmsg, msgT, nfB, wih, whh, wihB, whhB);
  k2_agg<<<(NN / 32) * KSPLIT, 512, 0, stream>>>(adj, msgT, aggP, degP);
  k3_gru<<<NN / 32, 512, 0, stream>>>(nf, aggP, degP, wihB, whhB, bih, bhh, nfB, out);
}